// Round 1
// baseline (29.050 us; speedup 1.0000x reference)
//
#include <hip/hip_runtime.h>

#define NNODE 8
#define FDIM 512
#define HDIM 256
#define ODIM 128
#define BATCH 8192
#define NEDGE (NNODE * (NNODE - 1))

#define FBLOCKS 8
#define FS (FDIM / FBLOCKS)   // 64 f-values per stage block
#define SPB 16                // samples per block in main kernel

// ws layout (floats): block k of stage kernel writes at k*9*HDIM:
//   [0..8*HDIM)  partial Y[n][h]   (n-major)
//   [8*HDIM..9*HDIM) partial s1[h]

__global__ __launch_bounds__(256) void gnn_stage(const float* __restrict__ nf,
                                                 const float* __restrict__ W1,
                                                 float* __restrict__ ws) {
    const int k = blockIdx.x;
    const int t = threadIdx.x;  // h index, 0..255
    __shared__ float nf_s[NNODE][FS];   // 8 x 64

    // load NF slice: 512 elements, 256 threads -> 2 each
    for (int idx = t; idx < NNODE * FS; idx += 256) {
        int n = idx / FS, f = idx % FS;
        nf_s[n][f] = nf[n * FDIM + k * FS + f];
    }
    __syncthreads();

    float s1 = 0.f;
    float y[NNODE];
#pragma unroll
    for (int n = 0; n < NNODE; n++) y[n] = 0.f;

    for (int ff = 0; ff < FS; ff++) {
        float wf = W1[(k * FS + ff) * HDIM + t];   // coalesced across t
        s1 += wf;
#pragma unroll
        for (int n = 0; n < NNODE; n++) y[n] = fmaf(nf_s[n][ff], wf, y[n]);
    }

    float* p = ws + (size_t)k * 9 * HDIM;
#pragma unroll
    for (int n = 0; n < NNODE; n++) p[n * HDIM + t] = y[n];
    p[8 * HDIM + t] = s1;
}

__global__ __launch_bounds__(256) void gnn_main(const float* __restrict__ latent,
                                                const float* __restrict__ edge_attr,
                                                const float* __restrict__ b1,
                                                const float* __restrict__ W2,
                                                const float* __restrict__ b2,
                                                const float* __restrict__ ws,
                                                float* __restrict__ out) {
    const int t = threadIdx.x;
    const int bs = blockIdx.x * SPB;

    __shared__ float Ahat_s[NNODE][NNODE];
    __shared__ float m_s[NNODE];
    __shared__ float w_s[SPB][NNODE];
    __shared__ float c_s[SPB][NNODE];
    __shared__ float g_s[SPB][HDIM];    // 16 KiB

    // ---- A_hat, m (single thread; ~300 trivial ops) ----
    if (t == 0) {
        float A[NNODE][NNODE];
        for (int i = 0; i < NNODE; i++)
            for (int j = 0; j < NNODE; j++) A[i][j] = (i == j) ? 1.f : 0.f;
        for (int e = 0; e < NEDGE; e++) {
            int i = e / (NNODE - 1);
            int jj = e % (NNODE - 1);
            int j = jj + (jj >= i ? 1 : 0);
            A[j][i] += edge_attr[e];   // A[DST][SRC] = w  (set on zero background)
        }
        float dinv[NNODE];
        for (int i = 0; i < NNODE; i++) {
            float d = 0.f;
            for (int j = 0; j < NNODE; j++) d += A[i][j];
            dinv[i] = d > 0.f ? 1.0f / sqrtf(d) : 0.f;
        }
        for (int i = 0; i < NNODE; i++)
            for (int j = 0; j < NNODE; j++) Ahat_s[i][j] = dinv[i] * A[i][j] * dinv[j];
        for (int j = 0; j < NNODE; j++) {
            float mm = 0.f;
            for (int i = 0; i < NNODE; i++) mm += Ahat_s[i][j];
            m_s[j] = mm * (1.0f / NNODE);
        }
    }

    // ---- load latent[:, :8] for this block's samples ----
    if (t < SPB * NNODE) {   // 128 threads
        int s = t >> 3, j = t & 7;
        w_s[s][j] = latent[(size_t)(bs + s) * FDIM + j];
    }
    __syncthreads();

    // ---- softmax over the 8 logits (redundant per lane, trivial) ----
    float wv = 0.f;
    if (t < SPB * NNODE) {
        int s = t >> 3, j = t & 7;
        float mx = -1e30f;
#pragma unroll
        for (int q = 0; q < NNODE; q++) mx = fmaxf(mx, w_s[s][q]);
        float sum = 0.f;
#pragma unroll
        for (int q = 0; q < NNODE; q++) sum += expf(w_s[s][q] - mx);
        wv = expf(w_s[s][j] - mx) / sum;
    }
    __syncthreads();
    if (t < SPB * NNODE) {
        int s = t >> 3, j = t & 7;
        w_s[s][j] = wv;
    }
    __syncthreads();

    // ---- c[s][i] = sum_j Ahat[i][j] * w[s][j] ----
    if (t < SPB * NNODE) {
        int s = t >> 3, i = t & 7;
        float c = 0.f;
#pragma unroll
        for (int j = 0; j < NNODE; j++) c = fmaf(Ahat_s[i][j], w_s[s][j], c);
        c_s[s][i] = c;
    }
    __syncthreads();

    // ---- reduce stage partials -> Y[.,t], s1[t]; then P[j][t] (registers) ----
    float Pj[NNODE];
    float s1t;
    {
        float y[NNODE];
        float s1 = 0.f;
#pragma unroll
        for (int n = 0; n < NNODE; n++) y[n] = 0.f;
        for (int k = 0; k < FBLOCKS; k++) {
            const float* p = ws + (size_t)k * 9 * HDIM;
#pragma unroll
            for (int n = 0; n < NNODE; n++) y[n] += p[n * HDIM + t];
            s1 += p[8 * HDIM + t];
        }
        s1t = s1;
        float bb = b1[t];
#pragma unroll
        for (int j = 0; j < NNODE; j++) {
            float acc = bb;
#pragma unroll
            for (int n = 0; n < NNODE; n++) acc = fmaf(Ahat_s[j][n], y[n], acc);
            Pj[j] = acc;
        }
    }

    // ---- g[s][t] = sum_j m[j] * relu(P[j][t] + 0.1*s1[t]*c[s][j]) ----
    {
        float s1t01 = 0.1f * s1t;
        float mreg[NNODE];
#pragma unroll
        for (int j = 0; j < NNODE; j++) mreg[j] = m_s[j];
        for (int s = 0; s < SPB; s++) {
            float g = 0.f;
#pragma unroll
            for (int j = 0; j < NNODE; j++) {
                float pre = fmaf(s1t01, c_s[s][j], Pj[j]);
                g = fmaf(mreg[j], fmaxf(pre, 0.f), g);
            }
            g_s[s][t] = g;
        }
    }
    __syncthreads();

    // ---- out[bs+s][o] = sum_h g[s][h]*W2[h][o] + b2[o] ----
    const int o = t & (ODIM - 1);
    const int grp = t >> 7;   // 0 or 1 -> samples grp*8 .. grp*8+7
    float acc[8];
#pragma unroll
    for (int k2 = 0; k2 < 8; k2++) acc[k2] = 0.f;

    for (int h = 0; h < HDIM; h += 4) {
        float w0 = W2[(h + 0) * ODIM + o];
        float w1 = W2[(h + 1) * ODIM + o];
        float w2v = W2[(h + 2) * ODIM + o];
        float w3 = W2[(h + 3) * ODIM + o];
#pragma unroll
        for (int k2 = 0; k2 < 8; k2++) {
            const float4 gv = *(const float4*)&g_s[grp * 8 + k2][h];  // ds_read_b128 broadcast
            acc[k2] = fmaf(gv.x, w0,
                      fmaf(gv.y, w1,
                      fmaf(gv.z, w2v,
                      fmaf(gv.w, w3, acc[k2]))));
        }
    }

    float bo = b2[o];
#pragma unroll
    for (int k2 = 0; k2 < 8; k2++) {
        out[(size_t)(bs + grp * 8 + k2) * ODIM + o] = acc[k2] + bo;
    }
}

extern "C" void kernel_launch(void* const* d_in, const int* in_sizes, int n_in,
                              void* d_out, int out_size, void* d_ws, size_t ws_size,
                              hipStream_t stream) {
    const float* latent = (const float*)d_in[0];
    const float* nf     = (const float*)d_in[1];
    const float* ea     = (const float*)d_in[2];
    const float* W1     = (const float*)d_in[3];
    const float* b1     = (const float*)d_in[4];
    const float* W2     = (const float*)d_in[5];
    const float* b2     = (const float*)d_in[6];
    float* out = (float*)d_out;
    float* ws  = (float*)d_ws;

    hipLaunchKernelGGL(gnn_stage, dim3(FBLOCKS), dim3(256), 0, stream, nf, W1, ws);
    hipLaunchKernelGGL(gnn_main, dim3(BATCH / SPB), dim3(256), 0, stream,
                       latent, ea, b1, W2, b2, ws, out);
}

// Round 2
// 29.007 us; speedup vs baseline: 1.0015x; 1.0015x over previous
//
#include <hip/hip_runtime.h>

#define NNODE 8
#define FDIM 512
#define HDIM 256
#define ODIM 128
#define BATCH 8192
#define NEDGE (NNODE * (NNODE - 1))

#define FBLOCKS 16
#define FS (FDIM / FBLOCKS)     // 32 f-values per stage block
#define SPB 16                  // samples per block in main kernel

// ws layout (floats):
//   stage partials: block k at k*9*HDIM : [8*HDIM) Y partials (n-major), [8*HDIM..9*HDIM) s1 partial
//   ws2 at WS2_OFF: P[8][256] | s1[256] | Ahat[64] | m[8]
#define WS2_OFF (FBLOCKS * 9 * HDIM)   // 36864
#define WS2_P 0
#define WS2_S1 (8 * HDIM)              // 2048
#define WS2_A (WS2_S1 + HDIM)          // 2304
#define WS2_M (WS2_A + 64)             // 2368

__global__ __launch_bounds__(256) void gnn_stage(const float* __restrict__ nf,
                                                 const float* __restrict__ W1,
                                                 float* __restrict__ ws) {
    const int k = blockIdx.x;
    const int t = threadIdx.x;  // h index
    __shared__ float nf_s[NNODE][FS];   // 8 x 32 = 256 floats

    {
        int n = t >> 5, f = t & 31;     // exactly 256 threads cover 8x32
        nf_s[n][f] = nf[n * FDIM + k * FS + f];
    }
    __syncthreads();

    float s1 = 0.f;
    float y[NNODE];
#pragma unroll
    for (int n = 0; n < NNODE; n++) y[n] = 0.f;

#pragma unroll
    for (int ff = 0; ff < FS; ff++) {
        float wf = W1[(k * FS + ff) * HDIM + t];   // coalesced across t
        s1 += wf;
#pragma unroll
        for (int n = 0; n < NNODE; n++) y[n] = fmaf(nf_s[n][ff], wf, y[n]);
    }

    float* p = ws + (size_t)k * 9 * HDIM;
#pragma unroll
    for (int n = 0; n < NNODE; n++) p[n * HDIM + t] = y[n];
    p[8 * HDIM + t] = s1;
}

__global__ __launch_bounds__(256) void gnn_mid(const float* __restrict__ edge_attr,
                                               const float* __restrict__ b1,
                                               float* __restrict__ ws) {
    const int t = threadIdx.x;   // h index
    float y[NNODE];
    float s1 = 0.f;
#pragma unroll
    for (int n = 0; n < NNODE; n++) y[n] = 0.f;
    for (int k = 0; k < FBLOCKS; k++) {
        const float* p = ws + (size_t)k * 9 * HDIM;
#pragma unroll
        for (int n = 0; n < NNODE; n++) y[n] += p[n * HDIM + t];
        s1 += p[8 * HDIM + t];
    }

    __shared__ float A_s[NNODE * NNODE];
    __shared__ float m_s[NNODE];
    if (t == 0) {
        float A[NNODE][NNODE];
        for (int i = 0; i < NNODE; i++)
            for (int j = 0; j < NNODE; j++) A[i][j] = (i == j) ? 1.f : 0.f;
        for (int e = 0; e < NEDGE; e++) {
            int i = e / (NNODE - 1);
            int jj = e % (NNODE - 1);
            int j = jj + (jj >= i ? 1 : 0);
            A[j][i] += edge_attr[e];   // A[DST][SRC]
        }
        float dinv[NNODE];
        for (int i = 0; i < NNODE; i++) {
            float d = 0.f;
            for (int j = 0; j < NNODE; j++) d += A[i][j];
            dinv[i] = d > 0.f ? 1.0f / sqrtf(d) : 0.f;
        }
        for (int i = 0; i < NNODE; i++)
            for (int j = 0; j < NNODE; j++) A_s[i * NNODE + j] = dinv[i] * A[i][j] * dinv[j];
        for (int j = 0; j < NNODE; j++) {
            float mm = 0.f;
            for (int i = 0; i < NNODE; i++) mm += A_s[i * NNODE + j];
            m_s[j] = mm * (1.0f / NNODE);
        }
    }
    __syncthreads();

    float* w2 = ws + WS2_OFF;
    float bb = b1[t];
#pragma unroll
    for (int j = 0; j < NNODE; j++) {
        float acc = bb;
#pragma unroll
        for (int n = 0; n < NNODE; n++) acc = fmaf(A_s[j * NNODE + n], y[n], acc);
        w2[WS2_P + j * HDIM + t] = acc;
    }
    w2[WS2_S1 + t] = s1;
    if (t < NNODE * NNODE) w2[WS2_A + t] = A_s[t];
    if (t < NNODE) w2[WS2_M + t] = m_s[t];
}

__global__ __launch_bounds__(256) void gnn_main(const float* __restrict__ latent,
                                                const float* __restrict__ W2,
                                                const float* __restrict__ b2,
                                                const float* __restrict__ ws,
                                                float* __restrict__ out) {
    const int t = threadIdx.x;
    const int bs = blockIdx.x * SPB;
    const float* wsp = ws + WS2_OFF;

    __shared__ float A_s[NNODE * NNODE];   // 256 B
    __shared__ float m_s[NNODE];           // 32 B
    __shared__ float lat_s[SPB][NNODE];    // 512 B
    __shared__ float c_s[SPB][NNODE];      // 512 B
    __shared__ float g_s[SPB][HDIM];       // 16 KiB
    __shared__ float wt[64 * ODIM];        // 32 KiB W2 tile

    // ---- setup loads ----
    if (t < NNODE * NNODE) A_s[t] = wsp[WS2_A + t];
    if (t >= 64 && t < 64 + NNODE) m_s[t - 64] = wsp[WS2_M + (t - 64)];
    if (t >= 128 && t < 128 + SPB * NNODE) {
        int u = t - 128;
        int s = u >> 3, j = u & 7;
        lat_s[s][j] = latent[(size_t)(bs + s) * FDIM + j];
    }
    // per-thread (h = t) layer-1 state
    float P[NNODE];
#pragma unroll
    for (int j = 0; j < NNODE; j++) P[j] = wsp[WS2_P + j * HDIM + t];
    float s1t = wsp[WS2_S1 + t];
    __syncthreads();

    // ---- softmax + c[s][i] = sum_j Ahat[i][j]*softmax_j (128 threads) ----
    if (t < SPB * NNODE) {
        int s = t >> 3, i = t & 7;
        float mx = -1e30f;
#pragma unroll
        for (int q = 0; q < NNODE; q++) mx = fmaxf(mx, lat_s[s][q]);
        float sum = 0.f, acc = 0.f;
#pragma unroll
        for (int q = 0; q < NNODE; q++) {
            float e = expf(lat_s[s][q] - mx);
            sum += e;
            acc = fmaf(A_s[i * NNODE + q], e, acc);
        }
        c_s[s][i] = acc / sum;
    }
    __syncthreads();

    // ---- g[s][h=t] = sum_j m[j]*relu(P[j] + 0.1*s1*c[s][j]) ----
    {
        float s101 = 0.1f * s1t;
        float mreg[NNODE];
#pragma unroll
        for (int j = 0; j < NNODE; j++) mreg[j] = m_s[j];
#pragma unroll 4
        for (int s = 0; s < SPB; s++) {
            float g = 0.f;
#pragma unroll
            for (int j = 0; j < NNODE; j++) {
                float pre = fmaf(s101, c_s[s][j], P[j]);
                g = fmaf(mreg[j], fmaxf(pre, 0.f), g);
            }
            g_s[s][t] = g;
        }
    }
    __syncthreads();

    // ---- GEMM: out[bs+s][o] = sum_h g[s][h]*W2[h][o] + b2[o] ----
    const int oq = t & 31;          // float4 column group: o = oq*4..oq*4+3
    const int sg = t >> 5;          // 0..7 -> samples sg*2, sg*2+1
    const int sa = sg * 2, sb = sg * 2 + 1;
    float4 acc0 = {0.f, 0.f, 0.f, 0.f};
    float4 acc1 = {0.f, 0.f, 0.f, 0.f};
    const float4* W2v = (const float4*)W2;
    float4* wtv = (float4*)wt;

    for (int tile = 0; tile < HDIM / 64; ++tile) {
        // stage 64x128 W2 tile: 2048 float4, 8 per thread, coalesced
#pragma unroll
        for (int i = 0; i < 8; ++i)
            wtv[t + 256 * i] = W2v[tile * 2048 + t + 256 * i];
        __syncthreads();

#pragma unroll
        for (int hh = 0; hh < 64; hh += 4) {
            const int hb = tile * 64 + hh;
            float4 ga = *(const float4*)&g_s[sa][hb];
            float4 gb = *(const float4*)&g_s[sb][hb];
            float4 w0 = *(const float4*)&wt[(hh + 0) * ODIM + oq * 4];
            float4 w1 = *(const float4*)&wt[(hh + 1) * ODIM + oq * 4];
            float4 w2r = *(const float4*)&wt[(hh + 2) * ODIM + oq * 4];
            float4 w3 = *(const float4*)&wt[(hh + 3) * ODIM + oq * 4];

            acc0.x = fmaf(ga.x, w0.x, acc0.x); acc0.y = fmaf(ga.x, w0.y, acc0.y);
            acc0.z = fmaf(ga.x, w0.z, acc0.z); acc0.w = fmaf(ga.x, w0.w, acc0.w);
            acc0.x = fmaf(ga.y, w1.x, acc0.x); acc0.y = fmaf(ga.y, w1.y, acc0.y);
            acc0.z = fmaf(ga.y, w1.z, acc0.z); acc0.w = fmaf(ga.y, w1.w, acc0.w);
            acc0.x = fmaf(ga.z, w2r.x, acc0.x); acc0.y = fmaf(ga.z, w2r.y, acc0.y);
            acc0.z = fmaf(ga.z, w2r.z, acc0.z); acc0.w = fmaf(ga.z, w2r.w, acc0.w);
            acc0.x = fmaf(ga.w, w3.x, acc0.x); acc0.y = fmaf(ga.w, w3.y, acc0.y);
            acc0.z = fmaf(ga.w, w3.z, acc0.z); acc0.w = fmaf(ga.w, w3.w, acc0.w);

            acc1.x = fmaf(gb.x, w0.x, acc1.x); acc1.y = fmaf(gb.x, w0.y, acc1.y);
            acc1.z = fmaf(gb.x, w0.z, acc1.z); acc1.w = fmaf(gb.x, w0.w, acc1.w);
            acc1.x = fmaf(gb.y, w1.x, acc1.x); acc1.y = fmaf(gb.y, w1.y, acc1.y);
            acc1.z = fmaf(gb.y, w1.z, acc1.z); acc1.w = fmaf(gb.y, w1.w, acc1.w);
            acc1.x = fmaf(gb.z, w2r.x, acc1.x); acc1.y = fmaf(gb.z, w2r.y, acc1.y);
            acc1.z = fmaf(gb.z, w2r.z, acc1.z); acc1.w = fmaf(gb.z, w2r.w, acc1.w);
            acc1.x = fmaf(gb.w, w3.x, acc1.x); acc1.y = fmaf(gb.w, w3.y, acc1.y);
            acc1.z = fmaf(gb.w, w3.z, acc1.z); acc1.w = fmaf(gb.w, w3.w, acc1.w);
        }
        __syncthreads();
    }

    float4 bo = *(const float4*)&b2[oq * 4];
    acc0.x += bo.x; acc0.y += bo.y; acc0.z += bo.z; acc0.w += bo.w;
    acc1.x += bo.x; acc1.y += bo.y; acc1.z += bo.z; acc1.w += bo.w;
    *(float4*)&out[(size_t)(bs + sa) * ODIM + oq * 4] = acc0;
    *(float4*)&out[(size_t)(bs + sb) * ODIM + oq * 4] = acc1;
}

extern "C" void kernel_launch(void* const* d_in, const int* in_sizes, int n_in,
                              void* d_out, int out_size, void* d_ws, size_t ws_size,
                              hipStream_t stream) {
    const float* latent = (const float*)d_in[0];
    const float* nf     = (const float*)d_in[1];
    const float* ea     = (const float*)d_in[2];
    const float* W1     = (const float*)d_in[3];
    const float* b1     = (const float*)d_in[4];
    const float* W2     = (const float*)d_in[5];
    const float* b2     = (const float*)d_in[6];
    float* out = (float*)d_out;
    float* ws  = (float*)d_ws;

    hipLaunchKernelGGL(gnn_stage, dim3(FBLOCKS), dim3(256), 0, stream, nf, W1, ws);
    hipLaunchKernelGGL(gnn_mid, dim3(1), dim3(256), 0, stream, ea, b1, ws);
    hipLaunchKernelGGL(gnn_main, dim3(BATCH / SPB), dim3(256), 0, stream,
                       latent, W2, b2, ws, out);
}